// Round 1
// baseline (16382.990 us; speedup 1.0000x reference)
//
#include <hip/hip_runtime.h>
#include <hip/hip_bf16.h>

// Problem constants (fixed by the reference)
#define NN   20000      // nodes
#define NE   320000     // edges
#define CC   256        // width
#define NHD  8          // heads
#define GSZ  32         // channels per group (CC/NHD)
#define CA   512        // width_act
#define OH   64         // outputs per head in grouped conv (CA/NHD)
#define TE   32         // edges per block in edge kernel

__device__ __forceinline__ void groupnorm32(float (&t)[32]) {
  float mu = 0.f;
  #pragma unroll
  for (int j = 0; j < 32; j++) mu += t[j];
  mu *= (1.f / 32.f);
  float var = 0.f;
  #pragma unroll
  for (int j = 0; j < 32; j++) { float d = t[j] - mu; var += d * d; }
  var *= (1.f / 32.f);
  float inv = rsqrtf(var + 1e-5f);
  #pragma unroll
  for (int j = 0; j < 32; j++) t[j] = (t[j] - mu) * inv;
}

// x0 = x @ w_src^T, x1 = x @ w_tgt^T   (blockIdx.y selects matrix)
__global__ __launch_bounds__(256) void proj_kernel(
    const float* __restrict__ x, const float* __restrict__ w_src,
    const float* __restrict__ w_tgt, float* __restrict__ x0,
    float* __restrict__ x1) {
  __shared__ float xs[32 * 256];
  const int tid = threadIdx.x;
  const int row0 = blockIdx.x * 32;
  const float* w = blockIdx.y ? w_tgt : w_src;
  float* out = blockIdx.y ? x1 : x0;

  const float4* src = (const float4*)(x + (size_t)row0 * CC);
  float4* dstv = (float4*)xs;
  for (int i = tid; i < 2048; i += 256) dstv[i] = src[i];
  __syncthreads();

  const int c = tid;
  float acc[32];
  #pragma unroll
  for (int r = 0; r < 32; r++) acc[r] = 0.f;
  for (int k = 0; k < 256; k += 4) {
    float4 wv = *(const float4*)(w + (size_t)c * CC + k);
    #pragma unroll
    for (int r = 0; r < 32; r++) {
      float4 xv = *(const float4*)(&xs[r * 256 + k]);
      acc[r] += xv.x * wv.x + xv.y * wv.y + xv.z * wv.z + xv.w * wv.w;
    }
  }
  #pragma unroll
  for (int r = 0; r < 32; r++) out[(size_t)(row0 + r) * CC + c] = acc[r];
}

__global__ void deg_kernel(const int* __restrict__ ei, float* __restrict__ deg) {
  int e = blockIdx.x * blockDim.x + threadIdx.x;
  if (e >= NE) return;
  int k0 = ei[e], k1 = ei[NE + e];
  if (k0 != k1) atomicAdd(&deg[k1], 1.0f);
}

// Fused per-edge pipeline: z-gather -> pre+GN -> gate/value -> post (bias)
//                          -> msg gather + GN -> gate(+bias)/value -> post -> scatter
__global__ __launch_bounds__(256, 1) void edge_kernel(
    const float* __restrict__ x0g, const float* __restrict__ x1g,
    const float* __restrict__ z_rw, const int* __restrict__ ei,
    const float* __restrict__ w_pre,
    const float* __restrict__ w_gate_p, const float* __restrict__ w_val_p,
    const float* __restrict__ w_post_p,
    const float* __restrict__ w_gate_f, const float* __restrict__ w_val_f,
    const float* __restrict__ w_post_f,
    float* __restrict__ xx) {
  __shared__ float WL[CA * GSZ];       // 64 KB weight staging
  __shared__ float ACC[TE][CC + 1];    // 32.9 KB bias/msg accumulator (padded)
  __shared__ float Zs[TE][33];         // 4.2 KB z staging (padded)
  __shared__ int K0s[TE], K1s[TE];

  const int tid = threadIdx.x;
  const int s = tid >> 5;      // group / head slice 0..7
  const int e = tid & 31;      // edge within tile
  const int ebase = blockIdx.x * TE;

  if (tid < TE) {
    K0s[tid] = ei[ebase + tid];
    K1s[tid] = ei[NE + ebase + tid];
  }
  for (int i = tid; i < TE * (CC + 1); i += 256) ((float*)ACC)[i] = 0.f;
  __syncthreads();

  // gather z = [z_rw[k0], z_rw[k1]]
  {
    int e2 = tid >> 3, q = tid & 7;
    int node = (q < 4) ? K0s[e2] : K1s[e2];
    int part = (q & 3) * 4;
    const float* srcz = z_rw + (size_t)node * 16 + part;
    int dbase = (q < 4 ? 0 : 16) + part;
    Zs[e2][dbase + 0] = srcz[0];
    Zs[e2][dbase + 1] = srcz[1];
    Zs[e2][dbase + 2] = srcz[2];
    Zs[e2][dbase + 3] = srcz[3];
  }
  // stage w_pre (256x32)
  for (int i = tid; i < CC * GSZ / 4; i += 256)
    ((float4*)WL)[i] = ((const float4*)w_pre)[i];
  __syncthreads();

  // ---- perw: pre-GEMM + groupnorm (fully in registers per (e, group s)) ----
  float z[32];
  #pragma unroll
  for (int k = 0; k < 32; k++) z[k] = Zs[e][k];
  float t[32];
  #pragma unroll
  for (int j = 0; j < 32; j++) {
    const float* wr = &WL[(s * GSZ + j) * GSZ];
    float a = 0.f;
    #pragma unroll
    for (int k = 0; k < 32; k++) a += z[k] * wr[k];
    t[j] = a;
  }
  groupnorm32(t);

  // gate (head s): stage w_gate_p, compute, relu
  __syncthreads();
  for (int i = tid; i < CA * GSZ / 4; i += 256)
    ((float4*)WL)[i] = ((const float4*)w_gate_p)[i];
  __syncthreads();
  float u[64];
  #pragma unroll
  for (int o = 0; o < 64; o++) {
    const float* wr = &WL[(s * OH + o) * GSZ];
    float a = 0.f;
    #pragma unroll
    for (int k = 0; k < 32; k++) a += t[k] * wr[k];
    u[o] = fmaxf(a, 0.f);
  }
  // value
  __syncthreads();
  for (int i = tid; i < CA * GSZ / 4; i += 256)
    ((float4*)WL)[i] = ((const float4*)w_val_p)[i];
  __syncthreads();
  #pragma unroll
  for (int o = 0; o < 64; o++) {
    const float* wr = &WL[(s * OH + o) * GSZ];
    float a = 0.f;
    #pragma unroll
    for (int k = 0; k < 32; k++) a += t[k] * wr[k];
    u[o] *= a;
  }

  // ---- perw post-GEMM -> bias in ACC ----
  for (int ch = 0; ch < 8; ch++) {
    __syncthreads();
    for (int i = tid; i < 32 * CA / 4; i += 256)
      ((float4*)WL)[i] = ((const float4*)(w_post_p + (size_t)ch * 32 * CA))[i];
    __syncthreads();
    #pragma unroll 4
    for (int cc = 0; cc < 32; cc++) {
      const float* wr = &WL[cc * CA + s * OH];
      float p = 0.f;
      #pragma unroll
      for (int o = 0; o < 64; o++) p += u[o] * wr[o];
      atomicAdd(&ACC[e][ch * 32 + cc], p);
    }
  }
  __syncthreads();  // bias complete

  // ---- ffn: msg = x0[k0] + x1[k1], groupnorm ----
  const int n0 = K0s[e], n1 = K1s[e];
  {
    const float* p0 = x0g + (size_t)n0 * CC + s * GSZ;
    const float* p1 = x1g + (size_t)n1 * CC + s * GSZ;
    #pragma unroll
    for (int j = 0; j < 32; j += 4) {
      float4 a = *(const float4*)(p0 + j);
      float4 b = *(const float4*)(p1 + j);
      t[j + 0] = a.x + b.x; t[j + 1] = a.y + b.y;
      t[j + 2] = a.z + b.z; t[j + 3] = a.w + b.w;
    }
  }
  groupnorm32(t);
  float gi[32];
  #pragma unroll
  for (int j = 0; j < 32; j++) gi[j] = t[j] + ACC[e][s * GSZ + j];
  __syncthreads();  // done reading bias

  // zero ACC for msg accumulation; stage w_gate_f
  for (int i = tid; i < TE * (CC + 1); i += 256) ((float*)ACC)[i] = 0.f;
  for (int i = tid; i < CA * GSZ / 4; i += 256)
    ((float4*)WL)[i] = ((const float4*)w_gate_f)[i];
  __syncthreads();
  #pragma unroll
  for (int o = 0; o < 64; o++) {
    const float* wr = &WL[(s * OH + o) * GSZ];
    float a = 0.f;
    #pragma unroll
    for (int k = 0; k < 32; k++) a += gi[k] * wr[k];
    u[o] = fmaxf(a, 0.f);
  }
  __syncthreads();
  for (int i = tid; i < CA * GSZ / 4; i += 256)
    ((float4*)WL)[i] = ((const float4*)w_val_f)[i];
  __syncthreads();
  #pragma unroll
  for (int o = 0; o < 64; o++) {
    const float* wr = &WL[(s * OH + o) * GSZ];
    float a = 0.f;
    #pragma unroll
    for (int k = 0; k < 32; k++) a += t[k] * wr[k];
    u[o] *= a;
  }

  // ---- ffn post-GEMM -> msg in ACC ----
  for (int ch = 0; ch < 8; ch++) {
    __syncthreads();
    for (int i = tid; i < 32 * CA / 4; i += 256)
      ((float4*)WL)[i] = ((const float4*)(w_post_f + (size_t)ch * 32 * CA))[i];
    __syncthreads();
    #pragma unroll 4
    for (int cc = 0; cc < 32; cc++) {
      const float* wr = &WL[cc * CA + s * OH];
      float p = 0.f;
      #pragma unroll
      for (int o = 0; o < 64; o++) p += u[o] * wr[o];
      atomicAdd(&ACC[e][ch * 32 + cc], p);
    }
  }
  __syncthreads();

  // scatter: xx[k1] += msg (masked)
  if (n0 != n1) {
    float* dst = xx + (size_t)n1 * CC + s * GSZ;
    #pragma unroll
    for (int j = 0; j < 32; j++) atomicAdd(dst + j, ACC[e][s * GSZ + j]);
  }
}

__global__ void finalize_kernel(const float* __restrict__ xx,
                                const float* __restrict__ deg,
                                const float* __restrict__ dp,
                                const float* __restrict__ x_res,
                                float* __restrict__ out) {
  int idx = blockIdx.x * blockDim.x + threadIdx.x;
  if (idx >= NN * CC) return;
  int n = idx >> 8, c = idx & 255;
  float d = fmaxf(deg[n], 1.0f);
  out[idx] = powf(d, dp[c]) * xx[idx] + x_res[idx];
}

extern "C" void kernel_launch(void* const* d_in, const int* in_sizes, int n_in,
                              void* d_out, int out_size, void* d_ws, size_t ws_size,
                              hipStream_t stream) {
  (void)in_sizes; (void)n_in; (void)out_size; (void)ws_size;
  const float* x        = (const float*)d_in[0];
  const float* x_res    = (const float*)d_in[1];
  const float* z_rw     = (const float*)d_in[2];
  const int*   ei       = (const int*)d_in[3];
  const float* w_src    = (const float*)d_in[4];
  const float* w_tgt    = (const float*)d_in[5];
  const float* w_pre    = (const float*)d_in[6];
  const float* w_gate_p = (const float*)d_in[7];
  const float* w_val_p  = (const float*)d_in[8];
  const float* w_post_p = (const float*)d_in[9];
  const float* w_gate_f = (const float*)d_in[10];
  const float* w_val_f  = (const float*)d_in[11];
  const float* w_post_f = (const float*)d_in[12];
  const float* dparam   = (const float*)d_in[13];
  float* out = (float*)d_out;

  float* wsf = (float*)d_ws;
  float* x0  = wsf;
  float* x1  = wsf + (size_t)NN * CC;
  float* xx  = wsf + 2 * (size_t)NN * CC;
  float* deg = wsf + 3 * (size_t)NN * CC;

  // zero xx and deg (contiguous)
  hipMemsetAsync(xx, 0, ((size_t)NN * CC + NN) * sizeof(float), stream);

  proj_kernel<<<dim3(NN / 32, 2), 256, 0, stream>>>(x, w_src, w_tgt, x0, x1);
  deg_kernel<<<(NE + 255) / 256, 256, 0, stream>>>(ei, deg);
  edge_kernel<<<NE / TE, 256, 0, stream>>>(x0, x1, z_rw, ei,
                                           w_pre, w_gate_p, w_val_p, w_post_p,
                                           w_gate_f, w_val_f, w_post_f, xx);
  finalize_kernel<<<(NN * CC + 255) / 256, 256, 0, stream>>>(xx, deg, dparam,
                                                             x_res, out);
}

// Round 2
// 1818.814 us; speedup vs baseline: 9.0075x; 9.0075x over previous
//
#include <hip/hip_runtime.h>
#include <hip/hip_bf16.h>

// Problem constants (fixed by the reference)
#define NN   20000      // nodes
#define NE   320000     // edges
#define CC   256        // width
#define CA   512        // width_act
#define ET   64         // edges per block in edge kernel

typedef __attribute__((ext_vector_type(8))) short s16x8;   // 8 bf16 (4 VGPRs)
typedef __attribute__((ext_vector_type(4))) float f32x4;   // MFMA accumulator

__device__ __forceinline__ unsigned short f2bf(float f) {
  unsigned int u = __float_as_uint(f);
  u += 0x7fff + ((u >> 16) & 1);          // RNE
  return (unsigned short)(u >> 16);
}
__device__ __forceinline__ float bf2f(unsigned short h) {
  return __uint_as_float(((unsigned int)h) << 16);
}

// ---------------- LDS layout (one 134KB block) ----------------
// R1: 65792 B : MS f32 [64][257] (pre-act / msg)  -> later u bf16 [64][512] swz
// R2: 33792 B : t/tv bf16 A-layout (stride 512B, swz) / bias bf16 [64][264]
// R3: 32768 B : Zs f32 [64][33] (perw) / tg bf16 A-layout (ffn)
// ST:  4096 B : stats f32 [64][8][2]
// K0/K1: 512 B
#define R1_OFF   0
#define R2_OFF   65792
#define R3_OFF   99584
#define ST_OFF   132352
#define K0_OFF   136448
#define K1_OFF   136704
#define SM_SIZE  136960

__device__ __forceinline__ int swzA(int row, int b) {   // 512B-stride regions
  return row * 512 + (b ^ ((row & 31) << 4));
}
__device__ __forceinline__ int swzU(int row, int b) {   // 1024B-stride u region
  return row * 1024 + (b ^ ((row & 31) << 4));
}

// ---------------- small kernels ----------------
__global__ void cvt_kernel(const float* __restrict__ s, unsigned short* __restrict__ d, int n) {
  int i = blockIdx.x * 256 + threadIdx.x;
  if (i < n) d[i] = f2bf(s[i]);
}

// x0 = x @ w_src^T, x1 = x @ w_tgt^T  (fp32 compute, bf16 out)
__global__ __launch_bounds__(256) void proj_kernel(
    const float* __restrict__ x, const float* __restrict__ w_src,
    const float* __restrict__ w_tgt, unsigned short* __restrict__ x0,
    unsigned short* __restrict__ x1) {
  __shared__ float xs[32 * 256];
  const int tid = threadIdx.x;
  const int row0 = blockIdx.x * 32;
  const float* w = blockIdx.y ? w_tgt : w_src;
  unsigned short* out = blockIdx.y ? x1 : x0;

  const float4* src = (const float4*)(x + (size_t)row0 * CC);
  float4* dstv = (float4*)xs;
  for (int i = tid; i < 2048; i += 256) dstv[i] = src[i];
  __syncthreads();

  const int c = tid;
  float acc[32];
  #pragma unroll
  for (int r = 0; r < 32; r++) acc[r] = 0.f;
  for (int k = 0; k < 256; k += 4) {
    float4 wv = *(const float4*)(w + (size_t)c * CC + k);
    #pragma unroll
    for (int r = 0; r < 32; r++) {
      float4 xv = *(const float4*)(&xs[r * 256 + k]);
      acc[r] += xv.x * wv.x + xv.y * wv.y + xv.z * wv.z + xv.w * wv.w;
    }
  }
  #pragma unroll
  for (int r = 0; r < 32; r++) out[(size_t)(row0 + r) * CC + c] = f2bf(acc[r]);
}

__global__ void deg_kernel(const int* __restrict__ ei, float* __restrict__ deg) {
  int e = blockIdx.x * blockDim.x + threadIdx.x;
  if (e >= NE) return;
  int k0 = ei[e], k1 = ei[NE + e];
  if (k0 != k1) atomicAdd(&deg[k1], 1.0f);
}

__global__ void finalize_kernel(const float* __restrict__ xx,
                                const float* __restrict__ deg,
                                const float* __restrict__ dp,
                                const float* __restrict__ x_res,
                                float* __restrict__ out) {
  int idx = blockIdx.x * blockDim.x + threadIdx.x;
  if (idx >= NN * CC) return;
  int n = idx >> 8, c = idx & 255;
  float d = fmaxf(deg[n], 1.0f);
  out[idx] = powf(d, dp[c]) * xx[idx] + x_res[idx];
}

// ---------------- fused MFMA edge kernel ----------------
__global__ __launch_bounds__(256, 1) void edge_mfma(
    const unsigned short* __restrict__ x0g, const unsigned short* __restrict__ x1g,
    const float* __restrict__ z_rw, const int* __restrict__ ei,
    const unsigned short* __restrict__ wpre,
    const unsigned short* __restrict__ wg_p, const unsigned short* __restrict__ wv_p,
    const unsigned short* __restrict__ wp_p,
    const unsigned short* __restrict__ wg_f, const unsigned short* __restrict__ wv_f,
    const unsigned short* __restrict__ wp_f,
    float* __restrict__ xx) {
  __shared__ __align__(16) char SM[SM_SIZE];
  float* MS = (float*)(SM + R1_OFF);                     // [64][257]
  char* R1b = SM + R1_OFF;
  char* R2b = SM + R2_OFF;
  unsigned short* BIAS = (unsigned short*)(SM + R2_OFF); // [64][264]
  char* R3b = SM + R3_OFF;
  float* Zs = (float*)(SM + R3_OFF);                     // [64][33]
  float* ST = (float*)(SM + ST_OFF);                     // [64][8][2]
  int* K0s = (int*)(SM + K0_OFF);
  int* K1s = (int*)(SM + K1_OFF);

  const int tid = threadIdx.x;
  const int lane = tid & 63;
  const int wv = tid >> 6;
  const int we0 = wv * 16;            // this wave's 16-edge tile
  const int arow = lane & 15;         // A-frag row / C col
  const int ahi = lane >> 4;          // k-chunk index
  const int ebase = blockIdx.x * ET;
  const f32x4 zero4 = {0.f, 0.f, 0.f, 0.f};

  // ---- staging: edge ids + z gather ----
  if (tid < ET) { K0s[tid] = ei[ebase + tid]; K1s[tid] = ei[NE + ebase + tid]; }
  {
    int e = tid >> 2, q = tid & 3;
    int node = ei[(q < 2 ? 0 : NE) + ebase + e];
    const float4* src = (const float4*)(z_rw + (size_t)node * 16);
    float4 v0 = src[(q & 1) * 2];
    float4 v1 = src[(q & 1) * 2 + 1];
    float* dz = &Zs[e * 33 + (q < 2 ? 0 : 16) + (q & 1) * 8];
    dz[0] = v0.x; dz[1] = v0.y; dz[2] = v0.z; dz[3] = v0.w;
    dz[4] = v1.x; dz[5] = v1.y; dz[6] = v1.z; dz[7] = v1.w;
  }
  __syncthreads();

  // ---- B: perw pre-GEMM  z[64,32] @ wpre^T -> MS fp32 ----
  {
    s16x8 az;
    const float* zp = &Zs[(we0 + arow) * 33 + ahi * 8];
    #pragma unroll
    for (int i = 0; i < 8; i++) az[i] = (short)f2bf(zp[i]);
    #pragma unroll
    for (int n = 0; n < 16; n++) {
      s16x8 b = *(const s16x8*)(wpre + (n * 16 + arow) * 32 + ahi * 8);
      f32x4 c = __builtin_amdgcn_mfma_f32_16x16x32_bf16(az, b, zero4, 0, 0, 0);
      #pragma unroll
      for (int r = 0; r < 4; r++)
        MS[(we0 + ahi * 4 + r) * 257 + n * 16 + arow] = c[r];
    }
  }
  __syncthreads();

  // ---- C: GroupNorm (perw) -> t into R2 (A-layout) ----
  #pragma unroll
  for (int rep = 0; rep < 2; rep++) {
    int h = (tid >> 6) + rep * 4;
    int e = tid & 63;
    const float* row = &MS[e * 257 + h * 32];
    float s1 = 0.f, s2 = 0.f;
    #pragma unroll
    for (int j = 0; j < 32; j++) { float v = row[j]; s1 += v; s2 += v * v; }
    float mu = s1 * (1.f / 32.f);
    float var = fmaxf(s2 * (1.f / 32.f) - mu * mu, 0.f);
    ST[(e * 8 + h) * 2] = mu;
    ST[(e * 8 + h) * 2 + 1] = rsqrtf(var + 1e-5f);
  }
  __syncthreads();
  #pragma unroll
  for (int it = 0; it < 8; it++) {
    int id = tid + 256 * it;
    int e = id & 63, ch = id >> 6, h = ch >> 2;
    float mu = ST[(e * 8 + h) * 2], rinv = ST[(e * 8 + h) * 2 + 1];
    const float* row = &MS[e * 257 + ch * 8];
    s16x8 v;
    #pragma unroll
    for (int i = 0; i < 8; i++) v[i] = (short)f2bf((row[i] - mu) * rinv);
    *(s16x8*)(R2b + swzA(e, ch * 16)) = v;
  }
  __syncthreads();

  // ---- D: perw grouped gate/value -> u into R1 (bf16, swz) ----
  #pragma unroll
  for (int h = 0; h < 8; h++) {
    s16x8 a = *(s16x8*)(R2b + swzA(we0 + arow, h * 64 + ahi * 16));
    f32x4 cg[4], cv[4];
    #pragma unroll
    for (int n = 0; n < 4; n++) {
      s16x8 bg = *(const s16x8*)(wg_p + (h * 64 + n * 16 + arow) * 32 + ahi * 8);
      cg[n] = __builtin_amdgcn_mfma_f32_16x16x32_bf16(a, bg, zero4, 0, 0, 0);
      s16x8 bv = *(const s16x8*)(wv_p + (h * 64 + n * 16 + arow) * 32 + ahi * 8);
      cv[n] = __builtin_amdgcn_mfma_f32_16x16x32_bf16(a, bv, zero4, 0, 0, 0);
    }
    #pragma unroll
    for (int n = 0; n < 4; n++)
      #pragma unroll
      for (int r = 0; r < 4; r++) {
        int e = we0 + ahi * 4 + r;
        int kcol = h * 64 + n * 16 + arow;
        *(unsigned short*)(R1b + swzU(e, kcol * 2)) =
            f2bf(fmaxf(cg[n][r], 0.f) * cv[n][r]);
      }
  }
  __syncthreads();

  // ---- E: perw post-GEMM u[64,512] @ wp_p^T -> bias in R2 ----
  {
    f32x4 acc[16];
    #pragma unroll
    for (int n = 0; n < 16; n++) acc[n] = zero4;
    #pragma unroll
    for (int ks = 0; ks < 16; ks++) {
      s16x8 a = *(s16x8*)(R1b + swzU(we0 + arow, ks * 64 + ahi * 16));
      #pragma unroll
      for (int n = 0; n < 16; n++) {
        s16x8 b = *(const s16x8*)(wp_p + (size_t)(n * 16 + arow) * 512 + ks * 32 + ahi * 8);
        acc[n] = __builtin_amdgcn_mfma_f32_16x16x32_bf16(a, b, acc[n], 0, 0, 0);
      }
    }
    #pragma unroll
    for (int n = 0; n < 16; n++)
      #pragma unroll
      for (int r = 0; r < 4; r++)
        BIAS[(we0 + ahi * 4 + r) * 264 + n * 16 + arow] = f2bf(acc[n][r]);
  }
  __syncthreads();

  // ---- F: ffn msg staging: MS = x0[k0] + x1[k1] ----
  {
    int e = tid >> 2, q = tid & 3;
    int k0 = K0s[e], k1 = K1s[e];
    const unsigned short* p0 = x0g + (size_t)k0 * 256 + q * 64;
    const unsigned short* p1 = x1g + (size_t)k1 * 256 + q * 64;
    float* dst = &MS[e * 257 + q * 64];
    #pragma unroll
    for (int c8 = 0; c8 < 8; c8++) {
      s16x8 a = *(const s16x8*)(p0 + c8 * 8);
      s16x8 b = *(const s16x8*)(p1 + c8 * 8);
      #pragma unroll
      for (int i = 0; i < 8; i++)
        dst[c8 * 8 + i] = bf2f((unsigned short)a[i]) + bf2f((unsigned short)b[i]);
    }
  }
  __syncthreads();

  // ---- G: GroupNorm (ffn) + bias -> tv(R2), tg(R3) ----
  #pragma unroll
  for (int rep = 0; rep < 2; rep++) {
    int h = (tid >> 6) + rep * 4;
    int e = tid & 63;
    const float* row = &MS[e * 257 + h * 32];
    float s1 = 0.f, s2 = 0.f;
    #pragma unroll
    for (int j = 0; j < 32; j++) { float v = row[j]; s1 += v; s2 += v * v; }
    float mu = s1 * (1.f / 32.f);
    float var = fmaxf(s2 * (1.f / 32.f) - mu * mu, 0.f);
    ST[(e * 8 + h) * 2] = mu;
    ST[(e * 8 + h) * 2 + 1] = rsqrtf(var + 1e-5f);
  }
  __syncthreads();
  {
    s16x8 tvp[8], tgp[8];
    #pragma unroll
    for (int it = 0; it < 8; it++) {
      int id = tid + 256 * it;
      int e = id & 63, ch = id >> 6, h = ch >> 2;
      float mu = ST[(e * 8 + h) * 2], rinv = ST[(e * 8 + h) * 2 + 1];
      const float* row = &MS[e * 257 + ch * 8];
      s16x8 bb = *(const s16x8*)(&BIAS[e * 264 + ch * 8]);
      s16x8 tv, tg;
      #pragma unroll
      for (int i = 0; i < 8; i++) {
        float v = (row[i] - mu) * rinv;
        tv[i] = (short)f2bf(v);
        tg[i] = (short)f2bf(v + bf2f((unsigned short)bb[i]));
      }
      tvp[it] = tv; tgp[it] = tg;
    }
    __syncthreads();   // all bias/msg reads done before overwriting R2
    #pragma unroll
    for (int it = 0; it < 8; it++) {
      int id = tid + 256 * it;
      int e = id & 63, ch = id >> 6;
      *(s16x8*)(R2b + swzA(e, ch * 16)) = tvp[it];
      *(s16x8*)(R3b + swzA(e, ch * 16)) = tgp[it];
    }
  }
  __syncthreads();

  // ---- H: ffn grouped gate/value -> u into R1 ----
  #pragma unroll
  for (int h = 0; h < 8; h++) {
    s16x8 av = *(s16x8*)(R2b + swzA(we0 + arow, h * 64 + ahi * 16));
    s16x8 ag = *(s16x8*)(R3b + swzA(we0 + arow, h * 64 + ahi * 16));
    f32x4 cg[4], cv[4];
    #pragma unroll
    for (int n = 0; n < 4; n++) {
      s16x8 bg = *(const s16x8*)(wg_f + (h * 64 + n * 16 + arow) * 32 + ahi * 8);
      cg[n] = __builtin_amdgcn_mfma_f32_16x16x32_bf16(ag, bg, zero4, 0, 0, 0);
      s16x8 bv = *(const s16x8*)(wv_f + (h * 64 + n * 16 + arow) * 32 + ahi * 8);
      cv[n] = __builtin_amdgcn_mfma_f32_16x16x32_bf16(av, bv, zero4, 0, 0, 0);
    }
    #pragma unroll
    for (int n = 0; n < 4; n++)
      #pragma unroll
      for (int r = 0; r < 4; r++) {
        int e = we0 + ahi * 4 + r;
        int kcol = h * 64 + n * 16 + arow;
        *(unsigned short*)(R1b + swzU(e, kcol * 2)) =
            f2bf(fmaxf(cg[n][r], 0.f) * cv[n][r]);
      }
  }
  __syncthreads();

  // ---- I: ffn post-GEMM -> msg, masked atomic scatter ----
  {
    f32x4 acc[16];
    #pragma unroll
    for (int n = 0; n < 16; n++) acc[n] = zero4;
    #pragma unroll
    for (int ks = 0; ks < 16; ks++) {
      s16x8 a = *(s16x8*)(R1b + swzU(we0 + arow, ks * 64 + ahi * 16));
      #pragma unroll
      for (int n = 0; n < 16; n++) {
        s16x8 b = *(const s16x8*)(wp_f + (size_t)(n * 16 + arow) * 512 + ks * 32 + ahi * 8);
        acc[n] = __builtin_amdgcn_mfma_f32_16x16x32_bf16(a, b, acc[n], 0, 0, 0);
      }
    }
    #pragma unroll
    for (int r = 0; r < 4; r++) {
      int e = we0 + ahi * 4 + r;
      int k0 = K0s[e], k1 = K1s[e];
      if (k0 != k1) {
        float* dst = xx + (size_t)k1 * 256;
        #pragma unroll
        for (int n = 0; n < 16; n++)
          atomicAdd(dst + n * 16 + arow, acc[n][r]);
      }
    }
  }
}

extern "C" void kernel_launch(void* const* d_in, const int* in_sizes, int n_in,
                              void* d_out, int out_size, void* d_ws, size_t ws_size,
                              hipStream_t stream) {
  (void)in_sizes; (void)n_in; (void)out_size; (void)ws_size;
  const float* x        = (const float*)d_in[0];
  const float* x_res    = (const float*)d_in[1];
  const float* z_rw     = (const float*)d_in[2];
  const int*   ei       = (const int*)d_in[3];
  const float* w_src    = (const float*)d_in[4];
  const float* w_tgt    = (const float*)d_in[5];
  const float* w_pre    = (const float*)d_in[6];
  const float* w_gate_p = (const float*)d_in[7];
  const float* w_val_p  = (const float*)d_in[8];
  const float* w_post_p = (const float*)d_in[9];
  const float* w_gate_f = (const float*)d_in[10];
  const float* w_val_f  = (const float*)d_in[11];
  const float* w_post_f = (const float*)d_in[12];
  const float* dparam   = (const float*)d_in[13];
  float* out = (float*)d_out;

  // workspace layout
  unsigned short* x0 = (unsigned short*)d_ws;
  unsigned short* x1 = x0 + (size_t)NN * CC;
  float* xx  = (float*)(x1 + (size_t)NN * CC);
  float* deg = xx + (size_t)NN * CC;
  unsigned short* wb = (unsigned short*)(deg + NN);
  unsigned short* wpre16 = wb;               // 8192
  unsigned short* wg_p16 = wpre16 + 8192;    // 16384
  unsigned short* wv_p16 = wg_p16 + 16384;   // 16384
  unsigned short* wp_p16 = wv_p16 + 16384;   // 131072
  unsigned short* wg_f16 = wp_p16 + 131072;  // 16384
  unsigned short* wv_f16 = wg_f16 + 16384;   // 16384
  unsigned short* wp_f16 = wv_f16 + 16384;   // 131072

  hipMemsetAsync(xx, 0, ((size_t)NN * CC + NN) * sizeof(float), stream);

  cvt_kernel<<<32, 256, 0, stream>>>(w_pre, wpre16, 8192);
  cvt_kernel<<<64, 256, 0, stream>>>(w_gate_p, wg_p16, 16384);
  cvt_kernel<<<64, 256, 0, stream>>>(w_val_p, wv_p16, 16384);
  cvt_kernel<<<512, 256, 0, stream>>>(w_post_p, wp_p16, 131072);
  cvt_kernel<<<64, 256, 0, stream>>>(w_gate_f, wg_f16, 16384);
  cvt_kernel<<<64, 256, 0, stream>>>(w_val_f, wv_f16, 16384);
  cvt_kernel<<<512, 256, 0, stream>>>(w_post_f, wp_f16, 131072);

  proj_kernel<<<dim3(NN / 32, 2), 256, 0, stream>>>(x, w_src, w_tgt, x0, x1);
  deg_kernel<<<(NE + 255) / 256, 256, 0, stream>>>(ei, deg);
  edge_mfma<<<NE / ET, 256, 0, stream>>>(x0, x1, z_rw, ei,
                                         wpre16, wg_p16, wv_p16, wp_p16,
                                         wg_f16, wv_f16, wp_f16, xx);
  finalize_kernel<<<(NN * CC + 255) / 256, 256, 0, stream>>>(xx, deg, dparam,
                                                             x_res, out);
}

// Round 3
// 940.057 us; speedup vs baseline: 17.4277x; 1.9348x over previous
//
#include <hip/hip_runtime.h>
#include <hip/hip_bf16.h>

// Problem constants (fixed by the reference)
#define NN   20000      // nodes
#define NE   320000     // edges
#define CC   256        // width
#define CA   512        // width_act
#define ET   32         // edges per block in edge kernel

typedef __attribute__((ext_vector_type(8))) short s16x8;   // 8 bf16 (4 VGPRs)
typedef __attribute__((ext_vector_type(4))) float f32x4;   // MFMA accumulator

__device__ __forceinline__ unsigned short f2bf(float f) {
  unsigned int u = __float_as_uint(f);
  u += 0x7fff + ((u >> 16) & 1);          // RNE
  return (unsigned short)(u >> 16);
}
__device__ __forceinline__ float bf2f(unsigned short h) {
  return __uint_as_float(((unsigned int)h) << 16);
}

// ---------------- LDS layout (69.25 KB -> 2 blocks/CU) ----------------
// T    : raw activations bf16 [32][256], stride 512B, swizzled
// BIAS : bias bf16 [32][256], stride 512B, swizzled
// U    : gated bf16 [32][512], stride 1024B, swizzled
// Z    : z bf16 [32][32], stride 80B (pad)
// ST   : stats f32 [32][20] (mu,rinv pairs at h*2, pad stride 20)
// K0/K1: edge ids
#define T_OFF    0
#define BIAS_OFF 16384
#define U_OFF    32768
#define Z_OFF    65536
#define ST_OFF   68096
#define K_OFF    70656
#define SM_SIZE  70912

// bank-safe swizzle: bits 4..6 mixed by row (bijective per row, rows spread)
__device__ __forceinline__ int swz(int row, int bcol) {
  return bcol ^ ((row & 7) << 4) ^ ((row & 8) << 2);
}

__device__ __forceinline__ s16x8 norm8(s16x8 v, float mu, float ri) {
  s16x8 o;
  #pragma unroll
  for (int i = 0; i < 8; i++)
    o[i] = (short)f2bf((bf2f((unsigned short)v[i]) - mu) * ri);
  return o;
}
__device__ __forceinline__ s16x8 addb(s16x8 a, s16x8 b) {
  s16x8 o;
  #pragma unroll
  for (int i = 0; i < 8; i++)
    o[i] = (short)f2bf(bf2f((unsigned short)a[i]) + bf2f((unsigned short)b[i]));
  return o;
}

// ---------------- small kernels ----------------
__global__ void cvt_kernel(const float* __restrict__ s, unsigned short* __restrict__ d, int n) {
  int i = blockIdx.x * 256 + threadIdx.x;
  if (i < n) d[i] = f2bf(s[i]);
}

__global__ __launch_bounds__(256) void proj_kernel(
    const float* __restrict__ x, const float* __restrict__ w_src,
    const float* __restrict__ w_tgt, unsigned short* __restrict__ x0,
    unsigned short* __restrict__ x1) {
  __shared__ float xs[32 * 256];
  const int tid = threadIdx.x;
  const int row0 = blockIdx.x * 32;
  const float* w = blockIdx.y ? w_tgt : w_src;
  unsigned short* out = blockIdx.y ? x1 : x0;

  const float4* src = (const float4*)(x + (size_t)row0 * CC);
  float4* dstv = (float4*)xs;
  for (int i = tid; i < 2048; i += 256) dstv[i] = src[i];
  __syncthreads();

  const int c = tid;
  float acc[32];
  #pragma unroll
  for (int r = 0; r < 32; r++) acc[r] = 0.f;
  for (int k = 0; k < 256; k += 4) {
    float4 wv = *(const float4*)(w + (size_t)c * CC + k);
    #pragma unroll
    for (int r = 0; r < 32; r++) {
      float4 xv = *(const float4*)(&xs[r * 256 + k]);
      acc[r] += xv.x * wv.x + xv.y * wv.y + xv.z * wv.z + xv.w * wv.w;
    }
  }
  #pragma unroll
  for (int r = 0; r < 32; r++) out[(size_t)(row0 + r) * CC + c] = f2bf(acc[r]);
}

__global__ void deg_kernel(const int* __restrict__ ei, float* __restrict__ deg) {
  int e = blockIdx.x * blockDim.x + threadIdx.x;
  if (e >= NE) return;
  int k0 = ei[e], k1 = ei[NE + e];
  if (k0 != k1) atomicAdd(&deg[k1], 1.0f);
}

__global__ void finalize_kernel(const float* __restrict__ xx,
                                const float* __restrict__ deg,
                                const float* __restrict__ dp,
                                const float* __restrict__ x_res,
                                float* __restrict__ out) {
  int idx = blockIdx.x * blockDim.x + threadIdx.x;
  if (idx >= NN * CC) return;
  int n = idx >> 8, c = idx & 255;
  float d = fmaxf(deg[n], 1.0f);
  out[idx] = powf(d, dp[c]) * xx[idx] + x_res[idx];
}

// ---------------- fused MFMA edge kernel ----------------
__global__ __launch_bounds__(256, 2) void edge_mfma(
    const unsigned short* __restrict__ x0g, const unsigned short* __restrict__ x1g,
    const float* __restrict__ z_rw, const int* __restrict__ ei,
    const unsigned short* __restrict__ wpre,
    const unsigned short* __restrict__ wg_p, const unsigned short* __restrict__ wv_p,
    const unsigned short* __restrict__ wp_p,
    const unsigned short* __restrict__ wg_f, const unsigned short* __restrict__ wv_f,
    const unsigned short* __restrict__ wp_f,
    float* __restrict__ xx) {
  __shared__ __align__(16) char SM[SM_SIZE];
  float* ST = (float*)(SM + ST_OFF);
  int* K0s = (int*)(SM + K_OFF);
  int* K1s = K0s + 32;

  const int tid = threadIdx.x;
  const int lane = tid & 63;
  const int w = tid >> 6;             // wave 0..3
  const int arow = lane & 15;
  const int ahi = lane >> 4;
  const int ebase = blockIdx.x * ET;
  const f32x4 zero4 = {0.f, 0.f, 0.f, 0.f};

  // ---- A: stage edge ids + z (bf16, A-layout [32][32], stride 80B) ----
  if (tid < ET) { K0s[tid] = ei[ebase + tid]; K1s[tid] = ei[NE + ebase + tid]; }
  {
    int e = tid >> 3, q = tid & 7;
    int node = ei[(q < 4 ? 0 : NE) + ebase + e];
    float4 v = *(const float4*)(z_rw + (size_t)node * 16 + (q & 3) * 4);
    unsigned int u0 = f2bf(v.x) | ((unsigned int)f2bf(v.y) << 16);
    unsigned int u1 = f2bf(v.z) | ((unsigned int)f2bf(v.w) << 16);
    *(uint2*)(SM + Z_OFF + e * 80 + q * 8) = make_uint2(u0, u1);
  }
  __syncthreads();

  // ---- B: perw pre-GEMM  z[32,32] @ wpre^T -> T raw bf16 ----
  {
    s16x8 a0 = *(const s16x8*)(SM + Z_OFF + arow * 80 + ahi * 16);
    s16x8 a1 = *(const s16x8*)(SM + Z_OFF + (16 + arow) * 80 + ahi * 16);
    #pragma unroll
    for (int nn = 0; nn < 4; nn++) {
      int n = w * 4 + nn;
      s16x8 b = *(const s16x8*)(wpre + (n * 16 + arow) * 32 + ahi * 8);
      f32x4 c0 = __builtin_amdgcn_mfma_f32_16x16x32_bf16(a0, b, zero4, 0, 0, 0);
      f32x4 c1 = __builtin_amdgcn_mfma_f32_16x16x32_bf16(a1, b, zero4, 0, 0, 0);
      int colb = (n * 16 + arow) * 2;
      #pragma unroll
      for (int r = 0; r < 4; r++) {
        int e0 = ahi * 4 + r, e1 = 16 + ahi * 4 + r;
        *(unsigned short*)(SM + T_OFF + e0 * 512 + swz(e0, colb)) = f2bf(c0[r]);
        *(unsigned short*)(SM + T_OFF + e1 * 512 + swz(e1, colb)) = f2bf(c1[r]);
      }
    }
  }
  __syncthreads();

  // ---- C: perw stats from raw bf16 T ----
  {
    int e = tid >> 3, h = tid & 7;
    float s1 = 0.f, s2 = 0.f;
    #pragma unroll
    for (int j = 0; j < 4; j++) {
      s16x8 v = *(const s16x8*)(SM + T_OFF + e * 512 + swz(e, h * 64 + j * 16));
      #pragma unroll
      for (int i = 0; i < 8; i++) {
        float f = bf2f((unsigned short)v[i]);
        s1 += f; s2 += f * f;
      }
    }
    float mu = s1 * (1.f / 32.f);
    float var = fmaxf(s2 * (1.f / 32.f) - mu * mu, 0.f);
    ST[e * 20 + h * 2] = mu;
    ST[e * 20 + h * 2 + 1] = rsqrtf(var + 1e-5f);
  }
  __syncthreads();

  // ---- D: perw grouped gate/value -> U ----
  #pragma unroll
  for (int hh = 0; hh < 2; hh++) {
    int h = w + hh * 4;
    float mu0 = ST[arow * 20 + h * 2],        ri0 = ST[arow * 20 + h * 2 + 1];
    float mu1 = ST[(16 + arow) * 20 + h * 2], ri1 = ST[(16 + arow) * 20 + h * 2 + 1];
    s16x8 t0 = *(const s16x8*)(SM + T_OFF + arow * 512 + swz(arow, h * 64 + ahi * 16));
    s16x8 t1 = *(const s16x8*)(SM + T_OFF + (16 + arow) * 512 + swz(16 + arow, h * 64 + ahi * 16));
    s16x8 a0 = norm8(t0, mu0, ri0);
    s16x8 a1 = norm8(t1, mu1, ri1);
    #pragma unroll
    for (int nn = 0; nn < 4; nn++) {
      int row = h * 64 + nn * 16 + arow;
      s16x8 bg = *(const s16x8*)(wg_p + row * 32 + ahi * 8);
      s16x8 bv = *(const s16x8*)(wv_p + row * 32 + ahi * 8);
      f32x4 g0 = __builtin_amdgcn_mfma_f32_16x16x32_bf16(a0, bg, zero4, 0, 0, 0);
      f32x4 v0 = __builtin_amdgcn_mfma_f32_16x16x32_bf16(a0, bv, zero4, 0, 0, 0);
      f32x4 g1 = __builtin_amdgcn_mfma_f32_16x16x32_bf16(a1, bg, zero4, 0, 0, 0);
      f32x4 v1 = __builtin_amdgcn_mfma_f32_16x16x32_bf16(a1, bv, zero4, 0, 0, 0);
      int colb = row * 2;
      #pragma unroll
      for (int r = 0; r < 4; r++) {
        int e0 = ahi * 4 + r, e1 = 16 + ahi * 4 + r;
        *(unsigned short*)(SM + U_OFF + e0 * 1024 + swz(e0, colb)) =
            f2bf(fmaxf(g0[r], 0.f) * v0[r]);
        *(unsigned short*)(SM + U_OFF + e1 * 1024 + swz(e1, colb)) =
            f2bf(fmaxf(g1[r], 0.f) * v1[r]);
      }
    }
  }
  __syncthreads();

  // ---- E: perw post-GEMM -> BIAS bf16 ----
  {
    f32x4 acc[2][4];
    #pragma unroll
    for (int a = 0; a < 2; a++)
      #pragma unroll
      for (int nn = 0; nn < 4; nn++) acc[a][nn] = zero4;
    #pragma unroll
    for (int ks = 0; ks < 16; ks++) {
      s16x8 a0 = *(const s16x8*)(SM + U_OFF + arow * 1024 + swz(arow, ks * 64 + ahi * 16));
      s16x8 a1 = *(const s16x8*)(SM + U_OFF + (16 + arow) * 1024 + swz(16 + arow, ks * 64 + ahi * 16));
      #pragma unroll
      for (int nn = 0; nn < 4; nn++) {
        s16x8 b = *(const s16x8*)(wp_p + (size_t)((w * 4 + nn) * 16 + arow) * 512 + ks * 32 + ahi * 8);
        acc[0][nn] = __builtin_amdgcn_mfma_f32_16x16x32_bf16(a0, b, acc[0][nn], 0, 0, 0);
        acc[1][nn] = __builtin_amdgcn_mfma_f32_16x16x32_bf16(a1, b, acc[1][nn], 0, 0, 0);
      }
    }
    #pragma unroll
    for (int a = 0; a < 2; a++)
      #pragma unroll
      for (int nn = 0; nn < 4; nn++) {
        int colb = ((w * 4 + nn) * 16 + arow) * 2;
        #pragma unroll
        for (int r = 0; r < 4; r++) {
          int e = a * 16 + ahi * 4 + r;
          *(unsigned short*)(SM + BIAS_OFF + e * 512 + swz(e, colb)) = f2bf(acc[a][nn][r]);
        }
      }
  }
  __syncthreads();

  // ---- F: ffn msg gather (x0[k0]+x1[k1]) -> T raw bf16 + stats ----
  {
    int e = tid >> 3, h = tid & 7;
    const unsigned short* p0 = x0g + (size_t)K0s[e] * 256 + h * 32;
    const unsigned short* p1 = x1g + (size_t)K1s[e] * 256 + h * 32;
    float s1 = 0.f, s2 = 0.f;
    #pragma unroll
    for (int j = 0; j < 4; j++) {
      s16x8 a = *(const s16x8*)(p0 + j * 8);
      s16x8 b = *(const s16x8*)(p1 + j * 8);
      s16x8 o;
      #pragma unroll
      for (int i = 0; i < 8; i++) {
        float f = bf2f((unsigned short)a[i]) + bf2f((unsigned short)b[i]);
        s1 += f; s2 += f * f;
        o[i] = (short)f2bf(f);
      }
      *(s16x8*)(SM + T_OFF + e * 512 + swz(e, h * 64 + j * 16)) = o;
    }
    float mu = s1 * (1.f / 32.f);
    float var = fmaxf(s2 * (1.f / 32.f) - mu * mu, 0.f);
    ST[e * 20 + h * 2] = mu;
    ST[e * 20 + h * 2 + 1] = rsqrtf(var + 1e-5f);
  }
  __syncthreads();

  // ---- G: ffn grouped gate(+bias)/value -> U ----
  #pragma unroll
  for (int hh = 0; hh < 2; hh++) {
    int h = w + hh * 4;
    float mu0 = ST[arow * 20 + h * 2],        ri0 = ST[arow * 20 + h * 2 + 1];
    float mu1 = ST[(16 + arow) * 20 + h * 2], ri1 = ST[(16 + arow) * 20 + h * 2 + 1];
    s16x8 t0 = *(const s16x8*)(SM + T_OFF + arow * 512 + swz(arow, h * 64 + ahi * 16));
    s16x8 t1 = *(const s16x8*)(SM + T_OFF + (16 + arow) * 512 + swz(16 + arow, h * 64 + ahi * 16));
    s16x8 b0 = *(const s16x8*)(SM + BIAS_OFF + arow * 512 + swz(arow, h * 64 + ahi * 16));
    s16x8 b1 = *(const s16x8*)(SM + BIAS_OFF + (16 + arow) * 512 + swz(16 + arow, h * 64 + ahi * 16));
    s16x8 a0v = norm8(t0, mu0, ri0);
    s16x8 a1v = norm8(t1, mu1, ri1);
    s16x8 a0g = addb(a0v, b0);
    s16x8 a1g = addb(a1v, b1);
    #pragma unroll
    for (int nn = 0; nn < 4; nn++) {
      int row = h * 64 + nn * 16 + arow;
      s16x8 bg = *(const s16x8*)(wg_f + row * 32 + ahi * 8);
      s16x8 bv = *(const s16x8*)(wv_f + row * 32 + ahi * 8);
      f32x4 g0 = __builtin_amdgcn_mfma_f32_16x16x32_bf16(a0g, bg, zero4, 0, 0, 0);
      f32x4 v0 = __builtin_amdgcn_mfma_f32_16x16x32_bf16(a0v, bv, zero4, 0, 0, 0);
      f32x4 g1 = __builtin_amdgcn_mfma_f32_16x16x32_bf16(a1g, bg, zero4, 0, 0, 0);
      f32x4 v1 = __builtin_amdgcn_mfma_f32_16x16x32_bf16(a1v, bv, zero4, 0, 0, 0);
      int colb = row * 2;
      #pragma unroll
      for (int r = 0; r < 4; r++) {
        int e0 = ahi * 4 + r, e1 = 16 + ahi * 4 + r;
        *(unsigned short*)(SM + U_OFF + e0 * 1024 + swz(e0, colb)) =
            f2bf(fmaxf(g0[r], 0.f) * v0[r]);
        *(unsigned short*)(SM + U_OFF + e1 * 1024 + swz(e1, colb)) =
            f2bf(fmaxf(g1[r], 0.f) * v1[r]);
      }
    }
  }
  __syncthreads();

  // ---- H: ffn post-GEMM -> masked atomic scatter ----
  {
    f32x4 acc[2][4];
    #pragma unroll
    for (int a = 0; a < 2; a++)
      #pragma unroll
      for (int nn = 0; nn < 4; nn++) acc[a][nn] = zero4;
    #pragma unroll
    for (int ks = 0; ks < 16; ks++) {
      s16x8 a0 = *(const s16x8*)(SM + U_OFF + arow * 1024 + swz(arow, ks * 64 + ahi * 16));
      s16x8 a1 = *(const s16x8*)(SM + U_OFF + (16 + arow) * 1024 + swz(16 + arow, ks * 64 + ahi * 16));
      #pragma unroll
      for (int nn = 0; nn < 4; nn++) {
        s16x8 b = *(const s16x8*)(wp_f + (size_t)((w * 4 + nn) * 16 + arow) * 512 + ks * 32 + ahi * 8);
        acc[0][nn] = __builtin_amdgcn_mfma_f32_16x16x32_bf16(a0, b, acc[0][nn], 0, 0, 0);
        acc[1][nn] = __builtin_amdgcn_mfma_f32_16x16x32_bf16(a1, b, acc[1][nn], 0, 0, 0);
      }
    }
    #pragma unroll
    for (int a = 0; a < 2; a++)
      #pragma unroll
      for (int r = 0; r < 4; r++) {
        int e = a * 16 + ahi * 4 + r;
        int k0 = K0s[e], k1 = K1s[e];
        if (k0 != k1) {
          float* dst = xx + (size_t)k1 * 256 + arow;
          #pragma unroll
          for (int nn = 0; nn < 4; nn++)
            atomicAdd(dst + (w * 4 + nn) * 16, acc[a][nn][r]);
        }
      }
  }
}

extern "C" void kernel_launch(void* const* d_in, const int* in_sizes, int n_in,
                              void* d_out, int out_size, void* d_ws, size_t ws_size,
                              hipStream_t stream) {
  (void)in_sizes; (void)n_in; (void)out_size; (void)ws_size;
  const float* x        = (const float*)d_in[0];
  const float* x_res    = (const float*)d_in[1];
  const float* z_rw     = (const float*)d_in[2];
  const int*   ei       = (const int*)d_in[3];
  const float* w_src    = (const float*)d_in[4];
  const float* w_tgt    = (const float*)d_in[5];
  const float* w_pre    = (const float*)d_in[6];
  const float* w_gate_p = (const float*)d_in[7];
  const float* w_val_p  = (const float*)d_in[8];
  const float* w_post_p = (const float*)d_in[9];
  const float* w_gate_f = (const float*)d_in[10];
  const float* w_val_f  = (const float*)d_in[11];
  const float* w_post_f = (const float*)d_in[12];
  const float* dparam   = (const float*)d_in[13];
  float* out = (float*)d_out;

  // workspace layout
  unsigned short* x0 = (unsigned short*)d_ws;
  unsigned short* x1 = x0 + (size_t)NN * CC;
  float* xx  = (float*)(x1 + (size_t)NN * CC);
  float* deg = xx + (size_t)NN * CC;
  unsigned short* wpre16 = (unsigned short*)(deg + NN);
  unsigned short* wg_p16 = wpre16 + 8192;
  unsigned short* wv_p16 = wg_p16 + 16384;
  unsigned short* wp_p16 = wv_p16 + 16384;
  unsigned short* wg_f16 = wp_p16 + 131072;
  unsigned short* wv_f16 = wg_f16 + 16384;
  unsigned short* wp_f16 = wv_f16 + 16384;

  hipMemsetAsync(xx, 0, ((size_t)NN * CC + NN) * sizeof(float), stream);

  cvt_kernel<<<32, 256, 0, stream>>>(w_pre, wpre16, 8192);
  cvt_kernel<<<64, 256, 0, stream>>>(w_gate_p, wg_p16, 16384);
  cvt_kernel<<<64, 256, 0, stream>>>(w_val_p, wv_p16, 16384);
  cvt_kernel<<<512, 256, 0, stream>>>(w_post_p, wp_p16, 131072);
  cvt_kernel<<<64, 256, 0, stream>>>(w_gate_f, wg_f16, 16384);
  cvt_kernel<<<64, 256, 0, stream>>>(w_val_f, wv_f16, 16384);
  cvt_kernel<<<512, 256, 0, stream>>>(w_post_f, wp_f16, 131072);

  proj_kernel<<<dim3(NN / 32, 2), 256, 0, stream>>>(x, w_src, w_tgt, x0, x1);
  deg_kernel<<<(NE + 255) / 256, 256, 0, stream>>>(ei, deg);
  edge_mfma<<<NE / ET, 256, 0, stream>>>(x0, x1, z_rw, ei,
                                         wpre16, wg_p16, wv_p16, wp_p16,
                                         wg_f16, wv_f16, wp_f16, xx);
  finalize_kernel<<<(NN * CC + 255) / 256, 256, 0, stream>>>(xx, deg, dparam,
                                                             x_res, out);
}